// Round 11
// baseline (369.683 us; speedup 1.0000x reference)
//
#include <hip/hip_runtime.h>
#include <math.h>

// ---------------- problem constants ----------------
#define NHEAD 4
#define LRELU_S 0.2f
constexpr int N_GT = 100000, N_AG = 20000;
constexpr int E_GT = 640000, E_COMM = 320000;
constexpr int OUTD = 5;
constexpr int NBLK_SC = (N_AG + 255) / 256;   // 79 scan blocks per graph
constexpr int MB_GT = (N_GT + 63) / 64;       // 1563
constexpr int ETILES  = (N_AG + 31) / 32;     // 625 (exact: 20000 = 625*32)
constexpr int GGROUPS = (N_AG + 3) / 4;       // 5000

// ---------------- workspace layout (float/u32 units of 4B) ----------------
constexpr long O_CNTP_GT = 0;          // 20000*16 u32 (dead before fs phase)
constexpr long O_CNTP_CM = 320000;
constexpr long O_FSB1    = 0;          // N_GT*64 bf16 (after CSR phases done)
constexpr long O_FSB2    = 3200000;    // N_GT*128 bf16
constexpr long O_EL1     = 12800000;
constexpr long O_EL2     = 13200000;
constexpr long O_ER1     = 14880000;
constexpr long O_RST2    = 17600000;   // h (persists)
constexpr long O_DINV    = 20160000;
constexpr long O_OFFS_GT = 20180000;
constexpr long O_SRT_GT  = 20200004;
constexpr long O_OFFS_CM = 20840004;
constexpr long O_SRT_CM  = 20860008;
constexpr long O_PART    = 21180008;
constexpr long O_V       = 21220008;
constexpr long O_WB      = 21300000;
constexpr long O_RANK_GT = 21500000;
constexpr long O_RANK_CM = 22140000;
constexpr long O_M  = 10240000;        // 20000*64 bf16 (fsb region dead in comm)

constexpr long WB_FS  = 0;
constexpr long WB_E1  = 6144;
constexpr long WB_E2  = 22528;
constexpr long WB_RZ  = 30720;
constexpr long WB_GIN = 112640;
constexpr long WB_GHN = 137216;

using bf8      = __attribute__((ext_vector_type(8))) short;
using f32x4v   = __attribute__((ext_vector_type(4))) float;
using ushort8v = __attribute__((ext_vector_type(8))) unsigned short;

__device__ __forceinline__ unsigned short f2bf(float x) {
    unsigned u = __float_as_uint(x);
    u += 0x7FFFu + ((u >> 16) & 1u);
    return (unsigned short)(u >> 16);
}
__device__ __forceinline__ float bf2f(unsigned short u) {
    return __uint_as_float(((unsigned)u) << 16);
}

// ==================== p0: zero counters + weight convert + attention vectors ====================
__global__ __launch_bounds__(256) void p0_k(
    const float* __restrict__ w1s, const float* __restrict__ w1d,
    const float* __restrict__ a1l, const float* __restrict__ a1r,
    const float* __restrict__ w2s, const float* __restrict__ w2d,
    const float* __restrict__ a2l, const float* __restrict__ a2r,
    const float* __restrict__ e1, const float* __restrict__ e2,
    const float* __restrict__ gih, const float* __restrict__ ghh,
    float* __restrict__ ws)
{
    const int tid = (int)(blockIdx.x * 256 + threadIdx.x);
    const int NT  = (int)(gridDim.x * 256);
    unsigned* wsu = reinterpret_cast<unsigned*>(ws);
    unsigned short* wb = reinterpret_cast<unsigned short*>(ws + O_WB);
    for (int i = tid; i < 640000; i += NT) wsu[O_CNTP_GT + i] = 0u;
    for (int i = tid; i < 153600; i += NT) {
        float val;
        if (i < 2048)        { long l = i;          long n = l / 32,  k = l % 32;  val = w1s[k * 64 + n]; }
        else if (i < 6144)   { long l = i - 2048;   long n = l / 32,  k = l % 32;  val = w2s[k * 128 + n]; }
        else if (i < 22528)  { long l = i - 6144;   long n = l / 128, k = l % 128; val = e1[k * 128 + n]; }
        else if (i < 30720)  { long l = i - 22528;  long n = l / 128, k = l % 128; val = e2[k * 64 + n]; }
        else if (i < 112640) { long l = i - 30720;  long n = l / 320, k = l % 320;
                               val = (k < 192) ? gih[k * 384 + n] : ghh[(k - 192) * 384 + n]; }
        else if (i < 137216) { long l = i - 112640; long n = l / 192, k = l % 192; val = gih[k * 384 + 256 + n]; }
        else                 { long l = i - 137216; long n = l / 128, k = l % 128; val = ghh[k * 384 + 256 + n]; }
        wb[i] = f2bf(val);
    }
    if (tid < 1024) {
        const int i = tid;
        const float *wp, *ap; int dh, local;
        if (i < 128)      { wp = w1s; ap = a1l; dh = 16; local = i; }
        else if (i < 384) { wp = w1d; ap = a1r; dh = 16; local = i - 128; }
        else if (i < 512) { wp = w2s; ap = a2l; dh = 32; local = i - 384; }
        else              { wp = w2d; ap = a2r; dh = 32; local = i - 512; }
        int k = local >> 2, hh = local & 3;
        float s = 0.f;
        for (int j = 0; j < dh; ++j) s += wp[k * (4 * dh) + hh * dh + j] * ap[hh * dh + j];
        ws[O_V + i] = s;
    }
}

// ==================== p1: count+rank (atomics) + rowvec el1/el2/er1 ====================
__global__ __launch_bounds__(256) void p1_k(
    const int* __restrict__ gt_dst, const int* __restrict__ comm_dst,
    const float* __restrict__ feat_gt, const float* __restrict__ feat_agent,
    float* __restrict__ ws)
{
    const int tid = (int)(blockIdx.x * 256 + threadIdx.x);
    unsigned* wsu = reinterpret_cast<unsigned*>(ws);
    if (tid < E_GT) {
        wsu[O_RANK_GT + tid] = atomicAdd(wsu + O_CNTP_GT + (long)gt_dst[tid] * 16, 1u);
    } else if (tid < E_GT + E_COMM) {
        int j = tid - E_GT;
        wsu[O_RANK_CM + j] = atomicAdd(wsu + O_CNTP_CM + (long)comm_dst[j] * 16, 1u);
    }
    const float* v1  = ws + O_V;
    const float* v2  = ws + O_V + 384;
    const float* vr1 = ws + O_V + 128;
    float* el1 = ws + O_EL1;
    float* el2 = ws + O_EL2;
    float* er1 = ws + O_ER1;
    if (tid < N_GT) {
        const int i = tid;
        float a[8] = {};
        const float* fp = feat_gt + (long)i * 32;
        for (int k = 0; k < 32; ++k) {
            float x = fp[k];
#pragma unroll
            for (int j = 0; j < 4; ++j) a[j] += x * v1[4 * k + j];
#pragma unroll
            for (int j = 0; j < 4; ++j) a[4 + j] += x * v2[4 * k + j];
        }
        *reinterpret_cast<float4*>(el1 + 4l * i) = {a[0], a[1], a[2], a[3]};
        *reinterpret_cast<float4*>(el2 + 4l * i) = {a[4], a[5], a[6], a[7]};
    } else if (tid < N_GT + N_AG) {
        int r = tid - N_GT;
        float a0 = 0, a1 = 0, a2 = 0, a3 = 0;
        const float* fp = feat_agent + (long)r * 64;
        for (int k = 0; k < 64; ++k) {
            float x = fp[k];
            a0 += x * vr1[4 * k];     a1 += x * vr1[4 * k + 1];
            a2 += x * vr1[4 * k + 2]; a3 += x * vr1[4 * k + 3];
        }
        *reinterpret_cast<float4*>(er1 + 4l * r) = {a0, a1, a2, a3};
    }
}

// ==================== p23: fused scan (direct cross-block prefix; counters are L2-resident) ====================
__global__ __launch_bounds__(256) void p23_k(float* __restrict__ ws)
{
    __shared__ unsigned shu[256];
    unsigned* wsu = reinterpret_cast<unsigned*>(ws);
    const int b = (int)blockIdx.x, t = (int)threadIdx.x;
    const int g  = (b >= NBLK_SC) ? 1 : 0;
    const int cb = b - g * NBLK_SC;
    const unsigned* cnt = wsu + (g ? O_CNTP_CM : O_CNTP_GT);

    // phase 1: cross-block prefix = sum of counts[0 .. cb*256)
    unsigned psum = 0u;
    for (int i = t; i < cb * 256; i += 256) psum += cnt[(long)i * 16];
    shu[t] = psum;
    __syncthreads();
    for (int off = 128; off >= 1; off >>= 1) {
        if (t < off) shu[t] += shu[t + off];
        __syncthreads();
    }
    const unsigned pre = shu[0];
    __syncthreads();

    // phase 2: own-block inclusive scan
    const int i = cb * 256 + t;
    unsigned c = (i < N_AG) ? cnt[(long)i * 16] : 0u;
    if (g && i < N_AG) ws[O_DINV + i] = 1.0f / fmaxf((float)c, 1.0f);
    shu[t] = c;
    __syncthreads();
    for (int off = 1; off < 256; off <<= 1) {
        unsigned v = (t >= off) ? shu[t - off] : 0u;
        __syncthreads();
        shu[t] += v;
        __syncthreads();
    }
    unsigned* offs = wsu + (g ? O_OFFS_CM : O_OFFS_GT);
    if (i < N_AG) offs[i] = pre + shu[t] - c;
    if (b == NBLK_SC - 1 && t == 0)     wsu[O_OFFS_GT + N_AG] = E_GT;
    if (b == 2 * NBLK_SC - 1 && t == 0) wsu[O_OFFS_CM + N_AG] = E_COMM;
}

// ==================== p4: place (grid-stride) + fs1+fs2 GEMM, 3 n-tiles per block ====================
__global__ __launch_bounds__(256) void p4_k(
    const int* __restrict__ gt_src, const int* __restrict__ gt_dst,
    const int* __restrict__ comm_src, const int* __restrict__ comm_dst,
    const float* __restrict__ A, float* __restrict__ ws)
{
    unsigned* wsu = reinterpret_cast<unsigned*>(ws);
    const int t = (int)threadIdx.x;
    const int NT = (int)(gridDim.x * 256);
    for (int i = (int)(blockIdx.x * 256 + t); i < E_GT + E_COMM; i += NT) {
        if (i < E_GT) {
            wsu[O_SRT_GT + wsu[O_OFFS_GT + gt_dst[i]] + wsu[O_RANK_GT + i]] = (unsigned)gt_src[i];
        } else {
            int j = i - E_GT;
            wsu[O_SRT_CM + wsu[O_OFFS_CM + comm_dst[j]] + wsu[O_RANK_CM + j]] = (unsigned)comm_src[j];
        }
    }

    __shared__ __align__(16) unsigned short As[64][40];
    __shared__ __align__(16) unsigned short Bs[192][40];
    const unsigned short* Btc = reinterpret_cast<unsigned short*>(ws + O_WB) + WB_FS;
    unsigned short* fsb1 = reinterpret_cast<unsigned short*>(ws + O_FSB1);
    unsigned short* fsb2 = reinterpret_cast<unsigned short*>(ws + O_FSB2);
    const int lane = t & 63, wv = t >> 6;
    const int wm = wv & 1, wn = wv >> 1;
    const int quad = lane >> 4, l16 = lane & 15;
    const int rA = t >> 3, cA = (t & 7) * 4;
    const int m0 = (int)blockIdx.x * 64;
    // stage A tile (64x32)
#pragma unroll
    for (int half = 0; half < 2; ++half) {
        const int r = rA + half * 32;
        const int row = m0 + r;
        float4 v = {0.f, 0.f, 0.f, 0.f};
        if (row < N_GT) v = *reinterpret_cast<const float4*>(A + (long)row * 32 + cA);
        ushort4 bb;
        bb.x = f2bf(v.x); bb.y = f2bf(v.y); bb.z = f2bf(v.z); bb.w = f2bf(v.w);
        *reinterpret_cast<ushort4*>(&As[r][cA]) = bb;
    }
    // stage all 192 B rows (192x32 shorts = 768 ushort8 chunks, 3 per thread)
#pragma unroll
    for (int it = 0; it < 3; ++it) {
        const int idx = t + it * 256;
        const int r = idx >> 2, c8 = (idx & 3) * 8;
        *reinterpret_cast<ushort8v*>(&Bs[r][c8]) =
            *reinterpret_cast<const ushort8v*>(Btc + (long)r * 32 + c8);
    }
    __syncthreads();
    const bf8 a0 = *reinterpret_cast<const bf8*>(&As[wm * 32 + l16][quad * 8]);
    const bf8 a1 = *reinterpret_cast<const bf8*>(&As[wm * 32 + 16 + l16][quad * 8]);
#pragma unroll
    for (int q = 0; q < 3; ++q) {
        const int n0 = q * 64;
        f32x4v acc[2][2] = {};
        const bf8 b0v = *reinterpret_cast<const bf8*>(&Bs[n0 + wn * 32 + l16][quad * 8]);
        const bf8 b1v = *reinterpret_cast<const bf8*>(&Bs[n0 + wn * 32 + 16 + l16][quad * 8]);
        acc[0][0] = __builtin_amdgcn_mfma_f32_16x16x32_bf16(a0, b0v, acc[0][0], 0, 0, 0);
        acc[0][1] = __builtin_amdgcn_mfma_f32_16x16x32_bf16(a0, b1v, acc[0][1], 0, 0, 0);
        acc[1][0] = __builtin_amdgcn_mfma_f32_16x16x32_bf16(a1, b0v, acc[1][0], 0, 0, 0);
        acc[1][1] = __builtin_amdgcn_mfma_f32_16x16x32_bf16(a1, b1v, acc[1][1], 0, 0, 0);
#pragma unroll
        for (int mt = 0; mt < 2; ++mt)
#pragma unroll
            for (int nt = 0; nt < 2; ++nt)
#pragma unroll
                for (int r = 0; r < 4; ++r) {
                    const int row = m0 + wm * 32 + mt * 16 + quad * 4 + r;
                    const int col = n0 + wn * 32 + nt * 16 + l16;
                    if (row < N_GT) {
                        unsigned short v16 = f2bf(acc[mt][nt][r]);
                        if (col < 64) fsb1[(long)row * 64 + col] = v16;
                        else          fsb2[(long)row * 128 + (col - 64)] = v16;
                    }
                }
    }
}

// ==================== fused GAT1+GAT2 (1 wave/dst, no-max softmax, scalar edge idx) ====================
__global__ __launch_bounds__(256) void gat12_k(
    const unsigned* __restrict__ offs, const unsigned* __restrict__ ssrc,
    const float* __restrict__ el1, const float* __restrict__ er1,
    const float* __restrict__ el2,
    const unsigned short* __restrict__ fsb1, const unsigned short* __restrict__ fsb2,
    const float* __restrict__ feat_agent,
    const float* __restrict__ b1, const float* __restrict__ b2,
    const float* __restrict__ vr2, float* __restrict__ out)
{
    const int wid = threadIdx.x >> 6, lane = threadIdx.x & 63;
    const int d = blockIdx.x * 4 + wid;
    if (d >= N_AG) return;
    const int h = lane >> 4, ei = lane & 15;
    const unsigned beg = __builtin_amdgcn_readfirstlane(offs[d]);
    const unsigned end = __builtin_amdgcn_readfirstlane(offs[d + 1]);
    const unsigned smax = (unsigned)N_GT - 1u;

    // -------- pass 1: GAT1 (CH=64) --------
    float s = 0.f, acc0 = 0.f;
    {
        const float er_h = er1[4l * d + h];
        for (unsigned base = beg; base < end; base += 16) {
            const unsigned na = min(16u, end - base);
            unsigned sv = ssrc[base + ((unsigned)ei < na ? (unsigned)ei : 0u)];
            sv = min(sv, smax);
            float p = 0.f;
            if ((unsigned)ei < na) {
                float x = el1[4l * sv + h] + er_h;
                x = (x >= 0.f) ? x : LRELU_S * x;
                p = __expf(x);
            }
            unsigned short fw[16];
#pragma unroll
            for (int j = 0; j < 16; ++j) {
                const unsigned sj = min(ssrc[min(base + (unsigned)j, end - 1u)], smax);
                fw[j] = fsb1[(long)sj * 64 + lane];
            }
#pragma unroll
            for (int j = 0; j < 16; ++j) {
                const float pj = __shfl(p, (h << 4) | j);
                s += pj;
                acc0 += pj * bf2f(fw[j]);
            }
        }
    }
    const float inv1 = (s > 0.f) ? 1.f / s : 0.f;
    const float r1 = feat_agent[(long)d * 64 + lane];
    const float o = fmaxf(acc0 * inv1 + r1 + b1[lane], 0.f);

    // er2 for this dst, fully in-register (butterfly sum over 64 lanes)
    float e0 = o * vr2[lane * 4 + 0] + r1 * vr2[(64 + lane) * 4 + 0];
    float e1v = o * vr2[lane * 4 + 1] + r1 * vr2[(64 + lane) * 4 + 1];
    float e2v = o * vr2[lane * 4 + 2] + r1 * vr2[(64 + lane) * 4 + 2];
    float e3v = o * vr2[lane * 4 + 3] + r1 * vr2[(64 + lane) * 4 + 3];
#pragma unroll
    for (int off = 1; off < 64; off <<= 1) {
        e0  += __shfl_xor(e0, off);
        e1v += __shfl_xor(e1v, off);
        e2v += __shfl_xor(e2v, off);
        e3v += __shfl_xor(e3v, off);
    }
    const float er_h2 = (h == 0) ? e0 : (h == 1) ? e1v : (h == 2) ? e2v : e3v;

    // -------- pass 2: GAT2 (CH=128) --------
    const int c0 = lane * 2;
    float s2 = 0.f, A0 = 0.f, A1 = 0.f;
    for (unsigned base = beg; base < end; base += 16) {
        const unsigned na = min(16u, end - base);
        unsigned sv = ssrc[base + ((unsigned)ei < na ? (unsigned)ei : 0u)];
        sv = min(sv, smax);
        float p = 0.f;
        if ((unsigned)ei < na) {
            float x = el2[4l * sv + h] + er_h2;
            x = (x >= 0.f) ? x : LRELU_S * x;
            p = __expf(x);
        }
        unsigned fw[16];
#pragma unroll
        for (int j = 0; j < 16; ++j) {
            const unsigned sj = min(ssrc[min(base + (unsigned)j, end - 1u)], smax);
            fw[j] = *reinterpret_cast<const unsigned*>(fsb2 + (long)sj * 128 + c0);
        }
#pragma unroll
        for (int j = 0; j < 16; ++j) {
            const float pj = __shfl(p, (h << 4) | j);
            s2 += pj;
            A0 += pj * __uint_as_float((fw[j] & 0xFFFFu) << 16);
            A1 += pj * __uint_as_float((fw[j] >> 16) << 16);
        }
    }
    const float inv2 = (s2 > 0.f) ? 1.f / s2 : 0.f;
    const float rox = __shfl(o, c0 & 63);
    const float roy = __shfl(o, (c0 + 1) & 63);
    float2 r;
    if (c0 < 64) { r.x = rox; r.y = roy; }
    else r = *reinterpret_cast<const float2*>(feat_agent + (long)d * 64 + (c0 - 64));
    float2 oo;
    oo.x = fmaxf(A0 * inv2 + r.x + b2[c0], 0.f);
    oo.y = fmaxf(A1 * inv2 + r.y + b2[c0 + 1], 0.f);
    *reinterpret_cast<float2*>(out + (long)d * 128 + c0) = oo;
}

// ==================== enc (512 threads): mb = relu(relu(h@E1+b1)@E2+b2) ====================
__global__ __launch_bounds__(512) void enc_k(
    const float* __restrict__ h,
    const unsigned short* __restrict__ we1, const unsigned short* __restrict__ we2,
    const float* __restrict__ eb1, const float* __restrict__ eb2,
    unsigned short* __restrict__ mb)
{
    __shared__ __align__(16) unsigned short As[32][136];
    __shared__ __align__(16) unsigned short Ts[32][136];
    const int tid = (int)threadIdx.x;
    const int lane = tid & 63, w = tid >> 6;
    const int quad = lane >> 4, l16 = lane & 15;
    const int m0 = (int)blockIdx.x * 32;
#pragma unroll
    for (int it = 0; it < 2; ++it) {
        int idx = tid + it * 512;
        int row = idx >> 5, cc = (idx & 31) * 4;
        int grow = m0 + row;
        float4 v = {0.f, 0.f, 0.f, 0.f};
        if (grow < N_AG) v = *reinterpret_cast<const float4*>(h + (long)grow * 128 + cc);
        ushort4 b;
        b.x = f2bf(v.x); b.y = f2bf(v.y); b.z = f2bf(v.z); b.w = f2bf(v.w);
        *reinterpret_cast<ushort4*>(&As[row][cc]) = b;
    }
    __syncthreads();
    {
        const int j0 = w * 16;
        const unsigned short* p = we1 + (long)(j0 + l16) * 128 + quad * 8;
        bf8 bw[4];
#pragma unroll
        for (int i = 0; i < 4; ++i) bw[i] = *reinterpret_cast<const bf8*>(p + i * 32);
        f32x4v acc[2] = {};
#pragma unroll
        for (int i = 0; i < 4; ++i) {
            const int k0 = i * 32;
            const bf8 a0 = *reinterpret_cast<const bf8*>(&As[l16][k0 + quad * 8]);
            const bf8 a1 = *reinterpret_cast<const bf8*>(&As[16 + l16][k0 + quad * 8]);
            acc[0] = __builtin_amdgcn_mfma_f32_16x16x32_bf16(a0, bw[i], acc[0], 0, 0, 0);
            acc[1] = __builtin_amdgcn_mfma_f32_16x16x32_bf16(a1, bw[i], acc[1], 0, 0, 0);
        }
        const int j = j0 + l16;
        const float bj = eb1[j];
#pragma unroll
        for (int mt = 0; mt < 2; ++mt)
#pragma unroll
            for (int r = 0; r < 4; ++r)
                Ts[mt * 16 + quad * 4 + r][j] = f2bf(fmaxf(acc[mt][r] + bj, 0.f));
    }
    __syncthreads();
    if (w < 4) {
        const int j0 = w * 16;
        const unsigned short* p = we2 + (long)(j0 + l16) * 128 + quad * 8;
        bf8 bw[4];
#pragma unroll
        for (int i = 0; i < 4; ++i) bw[i] = *reinterpret_cast<const bf8*>(p + i * 32);
        f32x4v acc[2] = {};
#pragma unroll
        for (int i = 0; i < 4; ++i) {
            const int k0 = i * 32;
            const bf8 a0 = *reinterpret_cast<const bf8*>(&Ts[l16][k0 + quad * 8]);
            const bf8 a1 = *reinterpret_cast<const bf8*>(&Ts[16 + l16][k0 + quad * 8]);
            acc[0] = __builtin_amdgcn_mfma_f32_16x16x32_bf16(a0, bw[i], acc[0], 0, 0, 0);
            acc[1] = __builtin_amdgcn_mfma_f32_16x16x32_bf16(a1, bw[i], acc[1], 0, 0, 0);
        }
        const int j = j0 + l16;
        const float bj = eb2[j];
#pragma unroll
        for (int mt = 0; mt < 2; ++mt)
#pragma unroll
            for (int r = 0; r < 4; ++r) {
                const int row = m0 + mt * 16 + quad * 4 + r;
                if (row < N_AG)
                    mb[(long)row * 64 + j] = f2bf(fmaxf(acc[mt][r] + bj, 0.f));
            }
    }
}

// ==================== GRU (512 threads) with fused mailbox-mean gather + output epilogue ====================
__global__ __launch_bounds__(512) void gru_k(
    const float* __restrict__ h_in,
    const unsigned* __restrict__ coffs, const unsigned* __restrict__ cssrc,
    const unsigned short* __restrict__ mbx, const float* __restrict__ dinv,
    const float* zz,
    const unsigned short* __restrict__ wrz, const unsigned short* __restrict__ wgin,
    const unsigned short* __restrict__ wghn,
    const float* __restrict__ gbih, const float* __restrict__ gbhh,
    float* hout,
    const float* __restrict__ ow, const float* __restrict__ ob, float* __restrict__ outp)
{
    __shared__ __align__(16) unsigned short As[32][328];   // 20992 B; reused as 32x128 f32 in epilogue
    __shared__ __align__(16) float Ys[32][64];             // 8192 B
    const int tid = (int)threadIdx.x;
    const int lane = tid & 63, w = tid >> 6;
    const int quad = lane >> 4, l16 = lane & 15;
    const int m0 = (int)blockIdx.x * 32;

    // ---- phase A: fused gather — y for this block's 32 rows ----
    {
        const unsigned smax = (unsigned)N_AG - 1u;
#pragma unroll 1
        for (int q = 0; q < 4; ++q) {
            const int d = m0 + w * 4 + q;
            const unsigned beg  = __builtin_amdgcn_readfirstlane(coffs[d]);
            const unsigned endo = __builtin_amdgcn_readfirstlane(coffs[d + 1]);
            float acc = 0.f;
            for (unsigned base = beg; base < endo; base += 32) {
                const unsigned na = min(32u, endo - base);
                unsigned short fw[32];
#pragma unroll
                for (int j = 0; j < 32; ++j) {
                    const unsigned sj = min(cssrc[min(base + (unsigned)j, endo - 1u)], smax);
                    fw[j] = mbx[(long)sj * 64 + lane];
                }
#pragma unroll
                for (int j = 0; j < 32; ++j)
                    if ((unsigned)j < na) acc += bf2f(fw[j]);
            }
            Ys[w * 4 + q][lane] = acc * dinv[d];
        }
    }
    __syncthreads();

    // ---- staging: [h | y(LDS) | zz] -> bf16 As ----
#pragma unroll
    for (int it = 0; it < 5; ++it) {
        int idx = tid + it * 512;
        int row = idx / 80, cc = (idx - row * 80) * 4;
        int grow = m0 + row;
        float4 v = {0.f, 0.f, 0.f, 0.f};
        if (grow < N_AG) {
            if (cc < 128)      v = *reinterpret_cast<const float4*>(h_in + (long)grow * 128 + cc);
            else if (cc < 192) v = *reinterpret_cast<const float4*>(&Ys[row][cc - 128]);
            else               v = *reinterpret_cast<const float4*>(zz + (long)grow * 128 + (cc - 192));
        }
        ushort4 b;
        b.x = f2bf(v.x); b.y = f2bf(v.y); b.z = f2bf(v.z); b.w = f2bf(v.w);
        *reinterpret_cast<ushort4*>(&As[row][cc]) = b;
    }
    __syncthreads();

    f32x4v aR[2] = {}, aZ[2] = {}, aI[2] = {}, aH[2] = {};
    const int j0 = w * 16;
    const unsigned short* pR = wrz + (long)(j0 + l16) * 320 + quad * 8;
    const unsigned short* pZ = wrz + (long)(128 + j0 + l16) * 320 + quad * 8;
#pragma unroll
    for (int half = 0; half < 2; ++half) {
        bf8 bR[5], bZ[5];
#pragma unroll
        for (int i = 0; i < 5; ++i) {
            const int k0 = half * 160 + i * 32;
            bR[i] = *reinterpret_cast<const bf8*>(pR + k0);
            bZ[i] = *reinterpret_cast<const bf8*>(pZ + k0);
        }
#pragma unroll
        for (int i = 0; i < 5; ++i) {
            const int k0 = half * 160 + i * 32;
            const bf8 a0 = *reinterpret_cast<const bf8*>(&As[l16][k0 + quad * 8]);
            const bf8 a1 = *reinterpret_cast<const bf8*>(&As[16 + l16][k0 + quad * 8]);
            aR[0] = __builtin_amdgcn_mfma_f32_16x16x32_bf16(a0, bR[i], aR[0], 0, 0, 0);
            aR[1] = __builtin_amdgcn_mfma_f32_16x16x32_bf16(a1, bR[i], aR[1], 0, 0, 0);
            aZ[0] = __builtin_amdgcn_mfma_f32_16x16x32_bf16(a0, bZ[i], aZ[0], 0, 0, 0);
            aZ[1] = __builtin_amdgcn_mfma_f32_16x16x32_bf16(a1, bZ[i], aZ[1], 0, 0, 0);
        }
    }
    {
        const unsigned short* pI = wgin + (long)(j0 + l16) * 192 + quad * 8;
        bf8 bI[6];
#pragma unroll
        for (int i = 0; i < 6; ++i) bI[i] = *reinterpret_cast<const bf8*>(pI + i * 32);
#pragma unroll
        for (int i = 0; i < 6; ++i) {
            const int k0 = i * 32;
            const bf8 a0 = *reinterpret_cast<const bf8*>(&As[l16][k0 + quad * 8]);
            const bf8 a1 = *reinterpret_cast<const bf8*>(&As[16 + l16][k0 + quad * 8]);
            aI[0] = __builtin_amdgcn_mfma_f32_16x16x32_bf16(a0, bI[i], aI[0], 0, 0, 0);
            aI[1] = __builtin_amdgcn_mfma_f32_16x16x32_bf16(a1, bI[i], aI[1], 0, 0, 0);
        }
    }
    {
        const unsigned short* pH = wghn + (long)(j0 + l16) * 128 + quad * 8;
        bf8 bH[4];
#pragma unroll
        for (int i = 0; i < 4; ++i) bH[i] = *reinterpret_cast<const bf8*>(pH + i * 32);
#pragma unroll
        for (int i = 0; i < 4; ++i) {
            const int k0 = 192 + i * 32;
            const bf8 a0 = *reinterpret_cast<const bf8*>(&As[l16][k0 + quad * 8]);
            const bf8 a1 = *reinterpret_cast<const bf8*>(&As[16 + l16][k0 + quad * 8]);
            aH[0] = __builtin_amdgcn_mfma_f32_16x16x32_bf16(a0, bH[i], aH[0], 0, 0, 0);
            aH[1] = __builtin_amdgcn_mfma_f32_16x16x32_bf16(a1, bH[i], aH[1], 0, 0, 0);
        }
    }
    const int j = j0 + l16;
    float hv[2][4];
#pragma unroll
    for (int mt = 0; mt < 2; ++mt)
#pragma unroll
        for (int r = 0; r < 4; ++r) {
            const int row = m0 + mt * 16 + quad * 4 + r;
            float v = 0.f;
            if (row < N_AG) {
                const float rr = 1.f / (1.f + __expf(-(aR[mt][r] + gbih[j] + gbhh[j])));
                const float zg = 1.f / (1.f + __expf(-(aZ[mt][r] + gbih[128 + j] + gbhh[128 + j])));
                const float nn = tanhf(aI[mt][r] + gbih[256 + j] + rr * (aH[mt][r] + gbhh[256 + j]));
                const float hp = zz[(long)row * 128 + j];
                v = (1.f - zg) * nn + zg * hp;
            }
            hv[mt][r] = v;
        }

    if (outp == nullptr) {
#pragma unroll
        for (int mt = 0; mt < 2; ++mt)
#pragma unroll
            for (int r = 0; r < 4; ++r) {
                const int row = m0 + mt * 16 + quad * 4 + r;
                if (row < N_AG) hout[(long)row * 128 + j] = hv[mt][r];
            }
    } else {
        __syncthreads();   // all MFMA reads of As done
        float* Hs = reinterpret_cast<float*>(&As[0][0]);   // 32x128 f32 = 16384 B <= 20992 B
#pragma unroll
        for (int mt = 0; mt < 2; ++mt)
#pragma unroll
            for (int r = 0; r < 4; ++r)
                Hs[(mt * 16 + quad * 4 + r) * 128 + j] = hv[mt][r];
        __syncthreads();
        for (int it = tid; it < 32 * 32; it += 512) {
            const int row = it >> 5, c4 = (it & 31) * 4;
            const float4 v = *reinterpret_cast<const float4*>(&Hs[row * 128 + c4]);
            *reinterpret_cast<float4*>(outp + (long)N_AG * OUTD + (long)(m0 + row) * 128 + c4) = v;
        }
        for (int it = tid; it < 32 * OUTD; it += 512) {
            const int row = it / OUTD, jj = it - row * OUTD;
            float a = ob[jj];
            const float* hr = &Hs[row * 128];
            for (int k = 0; k < 128; ++k) a += hr[k] * ow[k * OUTD + jj];
            outp[(long)(m0 + row) * OUTD + jj] = a;
        }
    }
}

// ==================== launcher ====================
extern "C" void kernel_launch(void* const* d_in, const int* in_sizes, int n_in,
                              void* d_out, int out_size, void* d_ws, size_t ws_size,
                              hipStream_t stream) {
    const float* feat_gt    = (const float*)d_in[0];
    const float* feat_agent = (const float*)d_in[1];
    const float* z_in       = (const float*)d_in[2];
    const int*   gt_src     = (const int*)d_in[3];
    const int*   gt_dst     = (const int*)d_in[4];
    const int*   comm_src   = (const int*)d_in[5];
    const int*   comm_dst   = (const int*)d_in[6];
    const float* w1_src = (const float*)d_in[7];
    const float* w1_dst = (const float*)d_in[8];
    const float* a1_l   = (const float*)d_in[9];
    const float* a1_r   = (const float*)d_in[10];
    const float* b1     = (const float*)d_in[11];
    const float* w2_src = (const float*)d_in[12];
    const float* w2_dst = (const float*)d_in[13];
    const float* a2_l   = (const float*)d_in[14];
    const float* a2_r   = (const float*)d_in[15];
    const float* b2     = (const float*)d_in[16];
    const float* enc_w1 = (const float*)d_in[17];
    const float* enc_b1 = (const float*)d_in[18];
    const float* enc_w2 = (const float*)d_in[19];
    const float* enc_b2 = (const float*)d_in[20];
    const float* gw_ih  = (const float*)d_in[21];
    const float* gw_hh  = (const float*)d_in[22];
    const float* gb_ih  = (const float*)d_in[23];
    const float* gb_hh  = (const float*)d_in[24];
    const float* out_w  = (const float*)d_in[25];
    const float* out_b  = (const float*)d_in[26];

    float* ws = (float*)d_ws;
    unsigned* wsu = (unsigned*)d_ws;
    unsigned short* wb = (unsigned short*)(ws + O_WB);
    float* out = (float*)d_out;

    float* hptr = ws + O_RST2;
    unsigned short* mb = (unsigned short*)(ws + O_M);

    p0_k<<<dim3(2500), dim3(256), 0, stream>>>(w1_src, w1_dst, a1_l, a1_r,
                                               w2_src, w2_dst, a2_l, a2_r,
                                               enc_w1, enc_w2, gw_ih, gw_hh, ws);
    p1_k<<<dim3(3750), dim3(256), 0, stream>>>(gt_dst, comm_dst, feat_gt, feat_agent, ws);
    p23_k<<<dim3(2 * NBLK_SC), dim3(256), 0, stream>>>(ws);
    p4_k<<<dim3(MB_GT), dim3(256), 0, stream>>>(gt_src, gt_dst, comm_src, comm_dst,
                                                feat_gt, ws);

    gat12_k<<<dim3(GGROUPS), dim3(256), 0, stream>>>(
        wsu + O_OFFS_GT, wsu + O_SRT_GT,
        ws + O_EL1, ws + O_ER1, ws + O_EL2,
        (const unsigned short*)(ws + O_FSB1), (const unsigned short*)(ws + O_FSB2),
        feat_agent, b1, b2, ws + O_V + 512, hptr);

    for (int step = 0; step < 2; ++step) {
        const float* zz = (step == 0) ? z_in : hptr;
        enc_k<<<dim3(ETILES), dim3(512), 0, stream>>>(hptr, wb + WB_E1, wb + WB_E2,
                                                      enc_b1, enc_b2, mb);
        gru_k<<<dim3(ETILES), dim3(512), 0, stream>>>(hptr,
                                                      wsu + O_OFFS_CM, wsu + O_SRT_CM,
                                                      mb, ws + O_DINV, zz,
                                                      wb + WB_RZ, wb + WB_GIN, wb + WB_GHN,
                                                      gb_ih, gb_hh, hptr,
                                                      (step == 1) ? out_w : nullptr,
                                                      (step == 1) ? out_b : nullptr,
                                                      (step == 1) ? out : nullptr);
    }
}

// Round 13
// 355.495 us; speedup vs baseline: 1.0399x; 1.0399x over previous
//
#include <hip/hip_runtime.h>
#include <math.h>

// ---------------- problem constants ----------------
#define NHEAD 4
#define LRELU_S 0.2f
constexpr int N_GT = 100000, N_AG = 20000;
constexpr int E_GT = 640000, E_COMM = 320000;
constexpr int OUTD = 5;
constexpr int NBLK_SC = (N_AG + 255) / 256;   // 79 scan blocks per graph
constexpr int MB_GT = (N_GT + 63) / 64;       // 1563
constexpr int FS_TILES = 3 * MB_GT;           // 4689
constexpr int ETILES  = (N_AG + 31) / 32;     // 625 (exact: 20000 = 625*32)
constexpr int GGROUPS = (N_AG + 3) / 4;       // 5000

// ---------------- workspace layout (float/u32 units of 4B) ----------------
constexpr long O_CNTP_GT = 0;          // 20000*16 u32 (dead before fs phase)
constexpr long O_CNTP_CM = 320000;
constexpr long O_FSB1    = 0;          // N_GT*64 bf16 (after CSR phases done)
constexpr long O_FSB2    = 3200000;    // N_GT*128 bf16
constexpr long O_EL1     = 12800000;
constexpr long O_EL2     = 13200000;
constexpr long O_ER1     = 14880000;
constexpr long O_RST2    = 17600000;   // h (persists)
constexpr long O_DINV    = 20160000;
constexpr long O_OFFS_GT = 20180000;
constexpr long O_SRT_GT  = 20200004;
constexpr long O_OFFS_CM = 20840004;
constexpr long O_SRT_CM  = 20860008;
constexpr long O_PART    = 21180008;
constexpr long O_V       = 21220008;
constexpr long O_WB      = 21300000;
constexpr long O_RANK_GT = 21500000;
constexpr long O_RANK_CM = 22140000;
constexpr long O_M  = 10240000;        // 20000*64 bf16 (fsb region dead in comm)

constexpr long WB_FS  = 0;
constexpr long WB_E1  = 6144;
constexpr long WB_E2  = 22528;
constexpr long WB_RZ  = 30720;
constexpr long WB_GIN = 112640;
constexpr long WB_GHN = 137216;

using bf8      = __attribute__((ext_vector_type(8))) short;
using f32x4v   = __attribute__((ext_vector_type(4))) float;
using ushort8v = __attribute__((ext_vector_type(8))) unsigned short;

__device__ __forceinline__ unsigned short f2bf(float x) {
    unsigned u = __float_as_uint(x);
    u += 0x7FFFu + ((u >> 16) & 1u);
    return (unsigned short)(u >> 16);
}
__device__ __forceinline__ float bf2f(unsigned short u) {
    return __uint_as_float(((unsigned)u) << 16);
}

// ==================== p0: zero counters + weight convert + attention vectors ====================
__global__ __launch_bounds__(256) void p0_k(
    const float* __restrict__ w1s, const float* __restrict__ w1d,
    const float* __restrict__ a1l, const float* __restrict__ a1r,
    const float* __restrict__ w2s, const float* __restrict__ w2d,
    const float* __restrict__ a2l, const float* __restrict__ a2r,
    const float* __restrict__ e1, const float* __restrict__ e2,
    const float* __restrict__ gih, const float* __restrict__ ghh,
    float* __restrict__ ws)
{
    const int tid = (int)(blockIdx.x * 256 + threadIdx.x);
    const int NT  = (int)(gridDim.x * 256);
    unsigned* wsu = reinterpret_cast<unsigned*>(ws);
    unsigned short* wb = reinterpret_cast<unsigned short*>(ws + O_WB);
    for (int i = tid; i < 640000; i += NT) wsu[O_CNTP_GT + i] = 0u;
    for (int i = tid; i < 153600; i += NT) {
        float val;
        if (i < 2048)        { long l = i;          long n = l / 32,  k = l % 32;  val = w1s[k * 64 + n]; }
        else if (i < 6144)   { long l = i - 2048;   long n = l / 32,  k = l % 32;  val = w2s[k * 128 + n]; }
        else if (i < 22528)  { long l = i - 6144;   long n = l / 128, k = l % 128; val = e1[k * 128 + n]; }
        else if (i < 30720)  { long l = i - 22528;  long n = l / 128, k = l % 128; val = e2[k * 64 + n]; }
        else if (i < 112640) { long l = i - 30720;  long n = l / 320, k = l % 320;
                               val = (k < 192) ? gih[k * 384 + n] : ghh[(k - 192) * 384 + n]; }
        else if (i < 137216) { long l = i - 112640; long n = l / 192, k = l % 192; val = gih[k * 384 + 256 + n]; }
        else                 { long l = i - 137216; long n = l / 128, k = l % 128; val = ghh[k * 384 + 256 + n]; }
        wb[i] = f2bf(val);
    }
    if (tid < 1024) {
        const int i = tid;
        const float *wp, *ap; int dh, local;
        if (i < 128)      { wp = w1s; ap = a1l; dh = 16; local = i; }
        else if (i < 384) { wp = w1d; ap = a1r; dh = 16; local = i - 128; }
        else if (i < 512) { wp = w2s; ap = a2l; dh = 32; local = i - 384; }
        else              { wp = w2d; ap = a2r; dh = 32; local = i - 512; }
        int k = local >> 2, hh = local & 3;
        float s = 0.f;
        for (int j = 0; j < dh; ++j) s += wp[k * (4 * dh) + hh * dh + j] * ap[hh * dh + j];
        ws[O_V + i] = s;
    }
}

// ==================== p1: count+rank (atomics) + rowvec el1/el2/er1 ====================
__global__ __launch_bounds__(256) void p1_k(
    const int* __restrict__ gt_dst, const int* __restrict__ comm_dst,
    const float* __restrict__ feat_gt, const float* __restrict__ feat_agent,
    float* __restrict__ ws)
{
    const int tid = (int)(blockIdx.x * 256 + threadIdx.x);
    unsigned* wsu = reinterpret_cast<unsigned*>(ws);
    if (tid < E_GT) {
        wsu[O_RANK_GT + tid] = atomicAdd(wsu + O_CNTP_GT + (long)gt_dst[tid] * 16, 1u);
    } else if (tid < E_GT + E_COMM) {
        int j = tid - E_GT;
        wsu[O_RANK_CM + j] = atomicAdd(wsu + O_CNTP_CM + (long)comm_dst[j] * 16, 1u);
    }
    const float* v1  = ws + O_V;
    const float* v2  = ws + O_V + 384;
    const float* vr1 = ws + O_V + 128;
    float* el1 = ws + O_EL1;
    float* el2 = ws + O_EL2;
    float* er1 = ws + O_ER1;
    if (tid < N_GT) {
        const int i = tid;
        float a[8] = {};
        const float* fp = feat_gt + (long)i * 32;
        for (int k = 0; k < 32; ++k) {
            float x = fp[k];
#pragma unroll
            for (int j = 0; j < 4; ++j) a[j] += x * v1[4 * k + j];
#pragma unroll
            for (int j = 0; j < 4; ++j) a[4 + j] += x * v2[4 * k + j];
        }
        *reinterpret_cast<float4*>(el1 + 4l * i) = {a[0], a[1], a[2], a[3]};
        *reinterpret_cast<float4*>(el2 + 4l * i) = {a[4], a[5], a[6], a[7]};
    } else if (tid < N_GT + N_AG) {
        int r = tid - N_GT;
        float a0 = 0, a1 = 0, a2 = 0, a3 = 0;
        const float* fp = feat_agent + (long)r * 64;
        for (int k = 0; k < 64; ++k) {
            float x = fp[k];
            a0 += x * vr1[4 * k];     a1 += x * vr1[4 * k + 1];
            a2 += x * vr1[4 * k + 2]; a3 += x * vr1[4 * k + 3];
        }
        *reinterpret_cast<float4*>(er1 + 4l * r) = {a0, a1, a2, a3};
    }
}

// ==================== p2/p3: two-phase scan ====================
__global__ __launch_bounds__(256) void p2_k(float* __restrict__ ws)
{
    __shared__ unsigned shu[256];
    unsigned* wsu = reinterpret_cast<unsigned*>(ws);
    const int b = (int)blockIdx.x, t = (int)threadIdx.x;
    const int g  = (b >= NBLK_SC) ? 1 : 0;
    const int cb = b - g * NBLK_SC;
    const int i  = cb * 256 + t;
    const unsigned* cnt = wsu + (g ? O_CNTP_CM : O_CNTP_GT);
    unsigned c = (i < N_AG) ? cnt[(long)i * 16] : 0u;
    if (g && i < N_AG) ws[O_DINV + i] = 1.0f / fmaxf((float)c, 1.0f);
    shu[t] = c;
    __syncthreads();
    for (int off = 1; off < 256; off <<= 1) {
        unsigned v = (t >= off) ? shu[t - off] : 0u;
        __syncthreads();
        shu[t] += v;
        __syncthreads();
    }
    unsigned* offs = wsu + (g ? O_OFFS_CM : O_OFFS_GT);
    if (i < N_AG) offs[i] = shu[t] - c;
    if (t == 255) wsu[O_PART + b] = shu[255];
}

__global__ __launch_bounds__(256) void p3_k(float* __restrict__ ws)
{
    __shared__ unsigned shu[128];
    unsigned* wsu = reinterpret_cast<unsigned*>(ws);
    const int b = (int)blockIdx.x, t = (int)threadIdx.x;
    const int g  = (b >= NBLK_SC) ? 1 : 0;
    const int cb = b - g * NBLK_SC;
    if (t < 128) shu[t] = (t < cb) ? wsu[O_PART + g * NBLK_SC + t] : 0u;
    __syncthreads();
    for (int off = 64; off >= 1; off >>= 1) {
        if (t < off) shu[t] += shu[t + off];
        __syncthreads();
    }
    const unsigned pre = shu[0];
    unsigned* offs = wsu + (g ? O_OFFS_CM : O_OFFS_GT);
    const int i = cb * 256 + t;
    if (i < N_AG) offs[i] += pre;
    if (b == NBLK_SC - 1 && t == 0)     wsu[O_OFFS_GT + N_AG] = E_GT;
    if (b == 2 * NBLK_SC - 1 && t == 0) wsu[O_OFFS_CM + N_AG] = E_COMM;
}

// ==================== p4: place (atomic-free) + fs1+fs2 GEMM ====================
__global__ __launch_bounds__(256) void p4_k(
    const int* __restrict__ gt_src, const int* __restrict__ gt_dst,
    const int* __restrict__ comm_src, const int* __restrict__ comm_dst,
    const float* __restrict__ A, float* __restrict__ ws)
{
    unsigned* wsu = reinterpret_cast<unsigned*>(ws);
    const int t = (int)threadIdx.x;
    const int tid = (int)(blockIdx.x * 256 + t);
    if (tid < E_GT) {
        wsu[O_SRT_GT + wsu[O_OFFS_GT + gt_dst[tid]] + wsu[O_RANK_GT + tid]] = (unsigned)gt_src[tid];
    } else if (tid < E_GT + E_COMM) {
        int j = tid - E_GT;
        wsu[O_SRT_CM + wsu[O_OFFS_CM + comm_dst[j]] + wsu[O_RANK_CM + j]] = (unsigned)comm_src[j];
    }

    __shared__ __align__(16) unsigned short As[64][40];
    __shared__ __align__(16) unsigned short Bs[64][40];
    const unsigned short* Btc = reinterpret_cast<unsigned short*>(ws + O_WB) + WB_FS;
    unsigned short* fsb1 = reinterpret_cast<unsigned short*>(ws + O_FSB1);
    unsigned short* fsb2 = reinterpret_cast<unsigned short*>(ws + O_FSB2);
    const int lane = t & 63, wv = t >> 6;
    const int wm = wv & 1, wn = wv >> 1;
    const int quad = lane >> 4, l16 = lane & 15;
    const int rA = t >> 3, cA = (t & 7) * 4;
    const int rB = t >> 2, cB = (t & 3) * 8;
    const int tt = (int)blockIdx.x;
    if (tt >= FS_TILES) return;
    const int n0 = (tt % 3) * 64, m0 = (tt / 3) * 64;
#pragma unroll
    for (int half = 0; half < 2; ++half) {
        const int r = rA + half * 32;
        const int row = m0 + r;
        float4 v = {0.f, 0.f, 0.f, 0.f};
        if (row < N_GT) v = *reinterpret_cast<const float4*>(A + (long)row * 32 + cA);
        ushort4 bb;
        bb.x = f2bf(v.x); bb.y = f2bf(v.y); bb.z = f2bf(v.z); bb.w = f2bf(v.w);
        *reinterpret_cast<ushort4*>(&As[r][cA]) = bb;
    }
    *reinterpret_cast<ushort8v*>(&Bs[rB][cB]) =
        *reinterpret_cast<const ushort8v*>(Btc + (long)(n0 + rB) * 32 + cB);
    __syncthreads();
    f32x4v acc[2][2] = {};
    const bf8 a0 = *reinterpret_cast<const bf8*>(&As[wm * 32 + l16][quad * 8]);
    const bf8 a1 = *reinterpret_cast<const bf8*>(&As[wm * 32 + 16 + l16][quad * 8]);
    const bf8 b0v = *reinterpret_cast<const bf8*>(&Bs[wn * 32 + l16][quad * 8]);
    const bf8 b1v = *reinterpret_cast<const bf8*>(&Bs[wn * 32 + 16 + l16][quad * 8]);
    acc[0][0] = __builtin_amdgcn_mfma_f32_16x16x32_bf16(a0, b0v, acc[0][0], 0, 0, 0);
    acc[0][1] = __builtin_amdgcn_mfma_f32_16x16x32_bf16(a0, b1v, acc[0][1], 0, 0, 0);
    acc[1][0] = __builtin_amdgcn_mfma_f32_16x16x32_bf16(a1, b0v, acc[1][0], 0, 0, 0);
    acc[1][1] = __builtin_amdgcn_mfma_f32_16x16x32_bf16(a1, b1v, acc[1][1], 0, 0, 0);
#pragma unroll
    for (int mt = 0; mt < 2; ++mt)
#pragma unroll
        for (int nt = 0; nt < 2; ++nt)
#pragma unroll
            for (int r = 0; r < 4; ++r) {
                const int row = m0 + wm * 32 + mt * 16 + quad * 4 + r;
                const int col = n0 + wn * 32 + nt * 16 + l16;
                if (row < N_GT) {
                    unsigned short v16 = f2bf(acc[mt][nt][r]);
                    if (col < 64) fsb1[(long)row * 64 + col] = v16;
                    else          fsb2[(long)row * 128 + (col - 64)] = v16;
                }
            }
}

// ==================== fused GAT1+GAT2 (1 wave/dst, no-max softmax + overflow clamp) ====================
// Softmax shift-invariance: scores here are |x| <~ 20, far from the exp overflow at 88.
// fminf(x, 60) is bit-identical in that regime and removes the only unbounded failure mode
// (inf/NaN propagation) under any pathological input/ordering.
__global__ __launch_bounds__(256) void gat12_k(
    const unsigned* __restrict__ offs, const unsigned* __restrict__ ssrc,
    const float* __restrict__ el1, const float* __restrict__ er1,
    const float* __restrict__ el2,
    const unsigned short* __restrict__ fsb1, const unsigned short* __restrict__ fsb2,
    const float* __restrict__ feat_agent,
    const float* __restrict__ b1, const float* __restrict__ b2,
    const float* __restrict__ vr2, float* __restrict__ out)
{
    const int wid = threadIdx.x >> 6, lane = threadIdx.x & 63;
    const int d = blockIdx.x * 4 + wid;
    if (d >= N_AG) return;
    const int h = lane >> 4, ei = lane & 15;
    const unsigned beg = __builtin_amdgcn_readfirstlane(offs[d]);
    const unsigned end = __builtin_amdgcn_readfirstlane(offs[d + 1]);
    const unsigned smax = (unsigned)N_GT - 1u;

    // -------- pass 1: GAT1 (CH=64) --------
    float s = 0.f, acc0 = 0.f;
    {
        const float er_h = er1[4l * d + h];
        for (unsigned base = beg; base < end; base += 16) {
            const unsigned na = min(16u, end - base);
            unsigned sv = ssrc[base + ((unsigned)ei < na ? (unsigned)ei : 0u)];
            sv = min(sv, smax);
            float p = 0.f;
            if ((unsigned)ei < na) {
                float x = el1[4l * sv + h] + er_h;
                x = (x >= 0.f) ? x : LRELU_S * x;
                p = __expf(fminf(x, 60.f));
            }
            unsigned short fw[16];
#pragma unroll
            for (int j = 0; j < 16; ++j) {
                const unsigned sj = min(ssrc[min(base + (unsigned)j, end - 1u)], smax);
                fw[j] = fsb1[(long)sj * 64 + lane];
            }
#pragma unroll
            for (int j = 0; j < 16; ++j) {
                const float pj = __shfl(p, (h << 4) | j);
                s += pj;
                acc0 += pj * bf2f(fw[j]);
            }
        }
    }
    const float inv1 = (s > 0.f) ? 1.f / s : 0.f;
    const float r1 = feat_agent[(long)d * 64 + lane];
    const float o = fmaxf(acc0 * inv1 + r1 + b1[lane], 0.f);

    // er2 for this dst, fully in-register (butterfly sum over 64 lanes)
    float e0 = o * vr2[lane * 4 + 0] + r1 * vr2[(64 + lane) * 4 + 0];
    float e1v = o * vr2[lane * 4 + 1] + r1 * vr2[(64 + lane) * 4 + 1];
    float e2v = o * vr2[lane * 4 + 2] + r1 * vr2[(64 + lane) * 4 + 2];
    float e3v = o * vr2[lane * 4 + 3] + r1 * vr2[(64 + lane) * 4 + 3];
#pragma unroll
    for (int off = 1; off < 64; off <<= 1) {
        e0  += __shfl_xor(e0, off);
        e1v += __shfl_xor(e1v, off);
        e2v += __shfl_xor(e2v, off);
        e3v += __shfl_xor(e3v, off);
    }
    const float er_h2 = (h == 0) ? e0 : (h == 1) ? e1v : (h == 2) ? e2v : e3v;

    // -------- pass 2: GAT2 (CH=128) --------
    const int c0 = lane * 2;
    float s2 = 0.f, A0 = 0.f, A1 = 0.f;
    for (unsigned base = beg; base < end; base += 16) {
        const unsigned na = min(16u, end - base);
        unsigned sv = ssrc[base + ((unsigned)ei < na ? (unsigned)ei : 0u)];
        sv = min(sv, smax);
        float p = 0.f;
        if ((unsigned)ei < na) {
            float x = el2[4l * sv + h] + er_h2;
            x = (x >= 0.f) ? x : LRELU_S * x;
            p = __expf(fminf(x, 60.f));
        }
        unsigned fw[16];
#pragma unroll
        for (int j = 0; j < 16; ++j) {
            const unsigned sj = min(ssrc[min(base + (unsigned)j, end - 1u)], smax);
            fw[j] = *reinterpret_cast<const unsigned*>(fsb2 + (long)sj * 128 + c0);
        }
#pragma unroll
        for (int j = 0; j < 16; ++j) {
            const float pj = __shfl(p, (h << 4) | j);
            s2 += pj;
            A0 += pj * __uint_as_float((fw[j] & 0xFFFFu) << 16);
            A1 += pj * __uint_as_float((fw[j] >> 16) << 16);
        }
    }
    const float inv2 = (s2 > 0.f) ? 1.f / s2 : 0.f;
    const float rox = __shfl(o, c0 & 63);
    const float roy = __shfl(o, (c0 + 1) & 63);
    float2 r;
    if (c0 < 64) { r.x = rox; r.y = roy; }
    else r = *reinterpret_cast<const float2*>(feat_agent + (long)d * 64 + (c0 - 64));
    float2 oo;
    oo.x = fmaxf(A0 * inv2 + r.x + b2[c0], 0.f);
    oo.y = fmaxf(A1 * inv2 + r.y + b2[c0 + 1], 0.f);
    *reinterpret_cast<float2*>(out + (long)d * 128 + c0) = oo;
}

// ==================== enc (512 threads): mb = relu(relu(h@E1+b1)@E2+b2) ====================
__global__ __launch_bounds__(512) void enc_k(
    const float* __restrict__ h,
    const unsigned short* __restrict__ we1, const unsigned short* __restrict__ we2,
    const float* __restrict__ eb1, const float* __restrict__ eb2,
    unsigned short* __restrict__ mb)
{
    __shared__ __align__(16) unsigned short As[32][136];
    __shared__ __align__(16) unsigned short Ts[32][136];
    const int tid = (int)threadIdx.x;
    const int lane = tid & 63, w = tid >> 6;
    const int quad = lane >> 4, l16 = lane & 15;
    const int m0 = (int)blockIdx.x * 32;
#pragma unroll
    for (int it = 0; it < 2; ++it) {
        int idx = tid + it * 512;
        int row = idx >> 5, cc = (idx & 31) * 4;
        int grow = m0 + row;
        float4 v = {0.f, 0.f, 0.f, 0.f};
        if (grow < N_AG) v = *reinterpret_cast<const float4*>(h + (long)grow * 128 + cc);
        ushort4 b;
        b.x = f2bf(v.x); b.y = f2bf(v.y); b.z = f2bf(v.z); b.w = f2bf(v.w);
        *reinterpret_cast<ushort4*>(&As[row][cc]) = b;
    }
    __syncthreads();
    {
        const int j0 = w * 16;
        const unsigned short* p = we1 + (long)(j0 + l16) * 128 + quad * 8;
        bf8 bw[4];
#pragma unroll
        for (int i = 0; i < 4; ++i) bw[i] = *reinterpret_cast<const bf8*>(p + i * 32);
        f32x4v acc[2] = {};
#pragma unroll
        for (int i = 0; i < 4; ++i) {
            const int k0 = i * 32;
            const bf8 a0 = *reinterpret_cast<const bf8*>(&As[l16][k0 + quad * 8]);
            const bf8 a1 = *reinterpret_cast<const bf8*>(&As[16 + l16][k0 + quad * 8]);
            acc[0] = __builtin_amdgcn_mfma_f32_16x16x32_bf16(a0, bw[i], acc[0], 0, 0, 0);
            acc[1] = __builtin_amdgcn_mfma_f32_16x16x32_bf16(a1, bw[i], acc[1], 0, 0, 0);
        }
        const int j = j0 + l16;
        const float bj = eb1[j];
#pragma unroll
        for (int mt = 0; mt < 2; ++mt)
#pragma unroll
            for (int r = 0; r < 4; ++r)
                Ts[mt * 16 + quad * 4 + r][j] = f2bf(fmaxf(acc[mt][r] + bj, 0.f));
    }
    __syncthreads();
    if (w < 4) {
        const int j0 = w * 16;
        const unsigned short* p = we2 + (long)(j0 + l16) * 128 + quad * 8;
        bf8 bw[4];
#pragma unroll
        for (int i = 0; i < 4; ++i) bw[i] = *reinterpret_cast<const bf8*>(p + i * 32);
        f32x4v acc[2] = {};
#pragma unroll
        for (int i = 0; i < 4; ++i) {
            const int k0 = i * 32;
            const bf8 a0 = *reinterpret_cast<const bf8*>(&Ts[l16][k0 + quad * 8]);
            const bf8 a1 = *reinterpret_cast<const bf8*>(&Ts[16 + l16][k0 + quad * 8]);
            acc[0] = __builtin_amdgcn_mfma_f32_16x16x32_bf16(a0, bw[i], acc[0], 0, 0, 0);
            acc[1] = __builtin_amdgcn_mfma_f32_16x16x32_bf16(a1, bw[i], acc[1], 0, 0, 0);
        }
        const int j = j0 + l16;
        const float bj = eb2[j];
#pragma unroll
        for (int mt = 0; mt < 2; ++mt)
#pragma unroll
            for (int r = 0; r < 4; ++r) {
                const int row = m0 + mt * 16 + quad * 4 + r;
                if (row < N_AG)
                    mb[(long)row * 64 + j] = f2bf(fmaxf(acc[mt][r] + bj, 0.f));
            }
    }
}

// ==================== GRU (512 threads) with fused mailbox-mean gather + output epilogue ====================
__global__ __launch_bounds__(512) void gru_k(
    const float* __restrict__ h_in,
    const unsigned* __restrict__ coffs, const unsigned* __restrict__ cssrc,
    const unsigned short* __restrict__ mbx, const float* __restrict__ dinv,
    const float* zz,
    const unsigned short* __restrict__ wrz, const unsigned short* __restrict__ wgin,
    const unsigned short* __restrict__ wghn,
    const float* __restrict__ gbih, const float* __restrict__ gbhh,
    float* hout,
    const float* __restrict__ ow, const float* __restrict__ ob, float* __restrict__ outp)
{
    __shared__ __align__(16) unsigned short As[32][328];   // 20992 B; reused as 32x128 f32 in epilogue
    __shared__ __align__(16) float Ys[32][64];             // 8192 B
    const int tid = (int)threadIdx.x;
    const int lane = tid & 63, w = tid >> 6;
    const int quad = lane >> 4, l16 = lane & 15;
    const int m0 = (int)blockIdx.x * 32;

    // ---- phase A: fused gather — y for this block's 32 rows ----
    {
        const unsigned smax = (unsigned)N_AG - 1u;
#pragma unroll 1
        for (int q = 0; q < 4; ++q) {
            const int d = m0 + w * 4 + q;
            const unsigned beg  = __builtin_amdgcn_readfirstlane(coffs[d]);
            const unsigned endo = __builtin_amdgcn_readfirstlane(coffs[d + 1]);
            float acc = 0.f;
            for (unsigned base = beg; base < endo; base += 32) {
                const unsigned na = min(32u, endo - base);
                unsigned short fw[32];
#pragma unroll
                for (int j = 0; j < 32; ++j) {
                    const unsigned sj = min(cssrc[min(base + (unsigned)j, endo - 1u)], smax);
                    fw[j] = mbx[(long)sj * 64 + lane];
                }
#pragma unroll
                for (int j = 0; j < 32; ++j)
                    if ((unsigned)j < na) acc += bf2f(fw[j]);
            }
            Ys[w * 4 + q][lane] = acc * dinv[d];
        }
    }
    __syncthreads();

    // ---- staging: [h | y(LDS) | zz] -> bf16 As ----
#pragma unroll
    for (int it = 0; it < 5; ++it) {
        int idx = tid + it * 512;
        int row = idx / 80, cc = (idx - row * 80) * 4;
        int grow = m0 + row;
        float4 v = {0.f, 0.f, 0.f, 0.f};
        if (grow < N_AG) {
            if (cc < 128)      v = *reinterpret_cast<const float4*>(h_in + (long)grow * 128 + cc);
            else if (cc < 192) v = *reinterpret_cast<const float4*>(&Ys[row][cc - 128]);
            else               v = *reinterpret_cast<const float4*>(zz + (long)grow * 128 + (cc - 192));
        }
        ushort4 b;
        b.x = f2bf(v.x); b.y = f2bf(v.y); b.z = f2bf(v.z); b.w = f2bf(v.w);
        *reinterpret_cast<ushort4*>(&As[row][cc]) = b;
    }
    __syncthreads();

    f32x4v aR[2] = {}, aZ[2] = {}, aI[2] = {}, aH[2] = {};
    const int j0 = w * 16;
    const unsigned short* pR = wrz + (long)(j0 + l16) * 320 + quad * 8;
    const unsigned short* pZ = wrz + (long)(128 + j0 + l16) * 320 + quad * 8;
#pragma unroll
    for (int half = 0; half < 2; ++half) {
        bf8 bR[5], bZ[5];
#pragma unroll
        for (int i = 0; i < 5; ++i) {
            const int k0 = half * 160 + i * 32;
            bR[i] = *reinterpret_cast<const bf8*>(pR + k0);
            bZ[i] = *reinterpret_cast<const bf8*>(pZ + k0);
        }
#pragma unroll
        for (int i = 0; i < 5; ++i) {
            const int k0 = half * 160 + i * 32;
            const bf8 a0 = *reinterpret_cast<const bf8*>(&As[l16][k0 + quad * 8]);
            const bf8 a1 = *reinterpret_cast<const bf8*>(&As[16 + l16][k0 + quad * 8]);
            aR[0] = __builtin_amdgcn_mfma_f32_16x16x32_bf16(a0, bR[i], aR[0], 0, 0, 0);
            aR[1] = __builtin_amdgcn_mfma_f32_16x16x32_bf16(a1, bR[i], aR[1], 0, 0, 0);
            aZ[0] = __builtin_amdgcn_mfma_f32_16x16x32_bf16(a0, bZ[i], aZ[0], 0, 0, 0);
            aZ[1] = __builtin_amdgcn_mfma_f32_16x16x32_bf16(a1, bZ[i], aZ[1], 0, 0, 0);
        }
    }
    {
        const unsigned short* pI = wgin + (long)(j0 + l16) * 192 + quad * 8;
        bf8 bI[6];
#pragma unroll
        for (int i = 0; i < 6; ++i) bI[i] = *reinterpret_cast<const bf8*>(pI + i * 32);
#pragma unroll
        for (int i = 0; i < 6; ++i) {
            const int k0 = i * 32;
            const bf8 a0 = *reinterpret_cast<const bf8*>(&As[l16][k0 + quad * 8]);
            const bf8 a1 = *reinterpret_cast<const bf8*>(&As[16 + l16][k0 + quad * 8]);
            aI[0] = __builtin_amdgcn_mfma_f32_16x16x32_bf16(a0, bI[i], aI[0], 0, 0, 0);
            aI[1] = __builtin_amdgcn_mfma_f32_16x16x32_bf16(a1, bI[i], aI[1], 0, 0, 0);
        }
    }
    {
        const unsigned short* pH = wghn + (long)(j0 + l16) * 128 + quad * 8;
        bf8 bH[4];
#pragma unroll
        for (int i = 0; i < 4; ++i) bH[i] = *reinterpret_cast<const bf8*>(pH + i * 32);
#pragma unroll
        for (int i = 0; i < 4; ++i) {
            const int k0 = 192 + i * 32;
            const bf8 a0 = *reinterpret_cast<const bf8*>(&As[l16][k0 + quad * 8]);
            const bf8 a1 = *reinterpret_cast<const bf8*>(&As[16 + l16][k0 + quad * 8]);
            aH[0] = __builtin_amdgcn_mfma_f32_16x16x32_bf16(a0, bH[i], aH[0], 0, 0, 0);
            aH[1] = __builtin_amdgcn_mfma_f32_16x16x32_bf16(a1, bH[i], aH[1], 0, 0, 0);
        }
    }
    const int j = j0 + l16;
    float hv[2][4];
#pragma unroll
    for (int mt = 0; mt < 2; ++mt)
#pragma unroll
        for (int r = 0; r < 4; ++r) {
            const int row = m0 + mt * 16 + quad * 4 + r;
            float v = 0.f;
            if (row < N_AG) {
                const float rr = 1.f / (1.f + __expf(-(aR[mt][r] + gbih[j] + gbhh[j])));
                const float zg = 1.f / (1.f + __expf(-(aZ[mt][r] + gbih[128 + j] + gbhh[128 + j])));
                const float nn = tanhf(aI[mt][r] + gbih[256 + j] + rr * (aH[mt][r] + gbhh[256 + j]));
                const float hp = zz[(long)row * 128 + j];
                v = (1.f - zg) * nn + zg * hp;
            }
            hv[mt][r] = v;
        }

    if (outp == nullptr) {
#pragma unroll
        for (int mt = 0; mt < 2; ++mt)
#pragma unroll
            for (int r = 0; r < 4; ++r) {
                const int row = m0 + mt * 16 + quad * 4 + r;
                if (row < N_AG) hout[(long)row * 128 + j] = hv[mt][r];
            }
    } else {
        __syncthreads();   // all MFMA reads of As done
        float* Hs = reinterpret_cast<float*>(&As[0][0]);   // 32x128 f32 = 16384 B <= 20992 B
#pragma unroll
        for (int mt = 0; mt < 2; ++mt)
#pragma unroll
            for (int r = 0; r < 4; ++r)
                Hs[(mt * 16 + quad * 4 + r) * 128 + j] = hv[mt][r];
        __syncthreads();
        for (int it = tid; it < 32 * 32; it += 512) {
            const int row = it >> 5, c4 = (it & 31) * 4;
            const float4 v = *reinterpret_cast<const float4*>(&Hs[row * 128 + c4]);
            *reinterpret_cast<float4*>(outp + (long)N_AG * OUTD + (long)(m0 + row) * 128 + c4) = v;
        }
        for (int it = tid; it < 32 * OUTD; it += 512) {
            const int row = it / OUTD, jj = it - row * OUTD;
            float a = ob[jj];
            const float* hr = &Hs[row * 128];
            for (int k = 0; k < 128; ++k) a += hr[k] * ow[k * OUTD + jj];
            outp[(long)(m0 + row) * OUTD + jj] = a;
        }
    }
}

// ==================== launcher ====================
extern "C" void kernel_launch(void* const* d_in, const int* in_sizes, int n_in,
                              void* d_out, int out_size, void* d_ws, size_t ws_size,
                              hipStream_t stream) {
    const float* feat_gt    = (const float*)d_in[0];
    const float* feat_agent = (const float*)d_in[1];
    const float* z_in       = (const float*)d_in[2];
    const int*   gt_src     = (const int*)d_in[3];
    const int*   gt_dst     = (const int*)d_in[4];
    const int*   comm_src   = (const int*)d_in[5];
    const int*   comm_dst   = (const int*)d_in[6];
    const float* w1_src = (const float*)d_in[7];
    const float* w1_dst = (const float*)d_in[8];
    const float* a1_l   = (const float*)d_in[9];
    const float* a1_r   = (const float*)d_in[10];
    const float* b1     = (const float*)d_in[11];
    const float* w2_src = (const float*)d_in[12];
    const float* w2_dst = (const float*)d_in[13];
    const float* a2_l   = (const float*)d_in[14];
    const float* a2_r   = (const float*)d_in[15];
    const float* b2     = (const float*)d_in[16];
    const float* enc_w1 = (const float*)d_in[17];
    const float* enc_b1 = (const float*)d_in[18];
    const float* enc_w2 = (const float*)d_in[19];
    const float* enc_b2 = (const float*)d_in[20];
    const float* gw_ih  = (const float*)d_in[21];
    const float* gw_hh  = (const float*)d_in[22];
    const float* gb_ih  = (const float*)d_in[23];
    const float* gb_hh  = (const float*)d_in[24];
    const float* out_w  = (const float*)d_in[25];
    const float* out_b  = (const float*)d_in[26];

    float* ws = (float*)d_ws;
    unsigned* wsu = (unsigned*)d_ws;
    unsigned short* wb = (unsigned short*)(ws + O_WB);
    float* out = (float*)d_out;

    float* hptr = ws + O_RST2;
    unsigned short* mb = (unsigned short*)(ws + O_M);

    p0_k<<<dim3(2500), dim3(256), 0, stream>>>(w1_src, w1_dst, a1_l, a1_r,
                                               w2_src, w2_dst, a2_l, a2_r,
                                               enc_w1, enc_w2, gw_ih, gw_hh, ws);
    p1_k<<<dim3(3750), dim3(256), 0, stream>>>(gt_dst, comm_dst, feat_gt, feat_agent, ws);
    p2_k<<<dim3(2 * NBLK_SC), dim3(256), 0, stream>>>(ws);
    p3_k<<<dim3(2 * NBLK_SC), dim3(256), 0, stream>>>(ws);
    p4_k<<<dim3(FS_TILES), dim3(256), 0, stream>>>(gt_src, gt_dst, comm_src, comm_dst,
                                                   feat_gt, ws);

    gat12_k<<<dim3(GGROUPS), dim3(256), 0, stream>>>(
        wsu + O_OFFS_GT, wsu + O_SRT_GT,
        ws + O_EL1, ws + O_ER1, ws + O_EL2,
        (const unsigned short*)(ws + O_FSB1), (const unsigned short*)(ws + O_FSB2),
        feat_agent, b1, b2, ws + O_V + 512, hptr);

    for (int step = 0; step < 2; ++step) {
        const float* zz = (step == 0) ? z_in : hptr;
        enc_k<<<dim3(ETILES), dim3(512), 0, stream>>>(hptr, wb + WB_E1, wb + WB_E2,
                                                      enc_b1, enc_b2, mb);
        gru_k<<<dim3(ETILES), dim3(512), 0, stream>>>(hptr,
                                                      wsu + O_OFFS_CM, wsu + O_SRT_CM,
                                                      mb, ws + O_DINV, zz,
                                                      wb + WB_RZ, wb + WB_GIN, wb + WB_GHN,
                                                      gb_ih, gb_hh, hptr,
                                                      (step == 1) ? out_w : nullptr,
                                                      (step == 1) ? out_b : nullptr,
                                                      (step == 1) ? out : nullptr);
    }
}